// Round 5
// baseline (268.250 us; speedup 1.0000x reference)
//
#include <hip/hip_runtime.h>

#define BN 262144
#define LNUM 15
#define LSTRIDE 1024            // floats per layer slab (992 used + emask + pad)
#define NET_SZ 496
#define OFF_BI 128
#define OFF_WH 136
#define OFF_BH 328
#define OFF_WO 352
#define OFF_BO 480
#define OFF_EMASK 992
#define INV_OFF (LNUM * LSTRIDE)  // int[16] lives here (float-index units)

// ---- setup: compose perms, build expanded per-layer weight slabs ----
// slab layout per layer l (floats):
//  net n in {0,1}: [n*496 + 0:128)  Wi_exp[p][h]  (16x8, rows = original slot)
//                  [128:136) bi  [136:328) Wh (3x8x8)  [328:352) bh (3x8)
//                  [352:480) Wo_exp[h][p] (8x16, cols = original slot)
//                  [480:496) bo_exp[p]
//  [992:1008) emask[p] (1e-6 on updated slots, else 0)
extern "C" __global__ void build_tabs(
    const float* __restrict__ Wi, const float* __restrict__ bi,
    const float* __restrict__ Wh, const float* __restrict__ bh,
    const float* __restrict__ Wo, const float* __restrict__ bo,
    const int* __restrict__ perms, float* __restrict__ ws) {
    __shared__ int c[(LNUM + 1) * 16];
    const int t = threadIdx.x;
    if (t == 0) {
        int cur[16];
        for (int j = 0; j < 16; ++j) { cur[j] = j; c[j] = j; }
        for (int l = 0; l < LNUM; ++l) {
            int nx[16];
            for (int j = 0; j < 16; ++j) nx[j] = cur[perms[l * 16 + j]];
            for (int j = 0; j < 16; ++j) { c[(l + 1) * 16 + j] = nx[j]; cur[j] = nx[j]; }
        }
    }
    __syncthreads();
    for (int idx = t; idx < LNUM * LSTRIDE; idx += blockDim.x) {
        const int l = idx / LSTRIDE;
        const int off = idx % LSTRIDE;
        const int* cl = &c[l * 16];
        float v = 0.f;
        if (off < OFF_EMASK) {
            const int n = off / NET_SZ;
            const int wo = off % NET_SZ;
            const int nb = l * 2 + n;
            if (wo < OFF_BI) {                    // Wi_exp[p][h]
                const int p = wo >> 3, h = wo & 7;
                for (int j = 0; j < 8; ++j)
                    if (cl[j] == p) v = Wi[(nb * 8 + j) * 8 + h];
            } else if (wo < OFF_WH) {
                v = bi[nb * 8 + (wo - OFF_BI)];
            } else if (wo < OFF_BH) {
                v = Wh[nb * 192 + (wo - OFF_WH)];
            } else if (wo < OFF_WO) {
                v = bh[nb * 24 + (wo - OFF_BH)];
            } else if (wo < OFF_BO) {             // Wo_exp[h][p]
                const int i2 = wo - OFF_WO;
                const int h = i2 >> 4, p = i2 & 15;
                for (int k = 0; k < 8; ++k)
                    if (cl[8 + k] == p) v = Wo[(nb * 8 + h) * 8 + k];
            } else {                              // bo_exp[p]
                const int p = wo - OFF_BO;
                for (int k = 0; k < 8; ++k)
                    if (cl[8 + k] == p) v = bo[nb * 8 + k];
            }
        } else if (off < OFF_EMASK + 16) {        // emask[p]
            const int p = off - OFF_EMASK;
            for (int k = 0; k < 8; ++k)
                if (cl[8 + k] == p) v = 1e-6f;
        }
        ws[idx] = v;
    }
    if (t < 16) {
        // y[j] = x_phys[c15[j]]  =>  store x[p] at y[inv[p]], inv[c15[t]] = t
        int* inv = (int*)(ws + INV_OFF);
        inv[c[LNUM * 16 + t]] = t;
    }
}

__device__ __forceinline__ void lrelu8(float v[8]) {
#pragma unroll
    for (int o = 0; o < 8; ++o) v[o] = fmaxf(v[o], 0.01f * v[o]);
}

// full expanded net: 16 phys inputs -> 16 phys outputs (zeros on pass-through)
__device__ __forceinline__ void net16(const float x[16], const float* __restrict__ W,
                                      float out[16]) {
    float h[8], g[8];
#pragma unroll
    for (int o = 0; o < 8; ++o) h[o] = W[OFF_BI + o];
#pragma unroll
    for (int p = 0; p < 16; ++p)
#pragma unroll
        for (int o = 0; o < 8; ++o) h[o] = fmaf(x[p], W[p * 8 + o], h[o]);
    lrelu8(h);
#pragma unroll
    for (int j = 0; j < 3; ++j) {
#pragma unroll
        for (int o = 0; o < 8; ++o) g[o] = W[OFF_BH + j * 8 + o];
#pragma unroll
        for (int ii = 0; ii < 8; ++ii)
#pragma unroll
            for (int o = 0; o < 8; ++o)
                g[o] = fmaf(h[ii], W[OFF_WH + j * 64 + ii * 8 + o], g[o]);
        lrelu8(g);
#pragma unroll
        for (int o = 0; o < 8; ++o) h[o] = g[o];
    }
#pragma unroll
    for (int p = 0; p < 16; ++p) out[p] = W[OFF_BO + p];
#pragma unroll
    for (int hh = 0; hh < 8; ++hh)
#pragma unroll
        for (int p = 0; p < 16; ++p)
            out[p] = fmaf(h[hh], W[OFF_WO + hh * 16 + p], out[p]);
}

// 1 thread = 1 sample; x stays in original slot order in registers forever.
// No LDS, no runtime register indexing; weights carry the permutation.
extern "C" __global__ void __launch_bounds__(256) flow_fwd(
    const float* __restrict__ z, const float* __restrict__ wsf,
    float* __restrict__ outy, float* __restrict__ outld) {
    const long i = (long)blockIdx.x * 256 + threadIdx.x;
    float x[16];
    {
        const float4* zp = reinterpret_cast<const float4*>(z + i * 16);
        float4 a0 = zp[0], a1 = zp[1], a2 = zp[2], a3 = zp[3];
        x[0] = a0.x;  x[1] = a0.y;  x[2] = a0.z;  x[3] = a0.w;
        x[4] = a1.x;  x[5] = a1.y;  x[6] = a1.z;  x[7] = a1.w;
        x[8] = a2.x;  x[9] = a2.y;  x[10] = a2.z; x[11] = a2.w;
        x[12] = a3.x; x[13] = a3.y; x[14] = a3.z; x[15] = a3.w;
    }
    float ld = 0.f;

    for (int l = 0; l < LNUM; ++l) {
        const float* __restrict__ Wb = wsf + l * LSTRIDE;  // block-uniform -> s_load
        float sf[16], bf[16];
        net16(x, Wb, sf);            // net 0: log_s (phys order, 0 on pass-through)
        net16(x, Wb + NET_SZ, bf);   // net 1: b
#pragma unroll
        for (int p = 0; p < 16; ++p) {
            const float cs = fminf(fmaxf(sf[p], -5.f), 5.f);
            ld += cs;                               // pass-through slots add 0
            const float m = __expf(cs) + Wb[OFF_EMASK + p];  // exact 1.0 on pass-through
            x[p] = fmaf(m, x[p], bf[p]);
        }
    }

    const int* __restrict__ inv = (const int*)(wsf + INV_OFF);
    float* __restrict__ yrow = outy + i * 16;
#pragma unroll
    for (int p = 0; p < 16; ++p) yrow[inv[p]] = x[p];   // static regs, runtime addr
    outld[i] = ld;
}

extern "C" void kernel_launch(void* const* d_in, const int* in_sizes, int n_in,
                              void* d_out, int out_size, void* d_ws, size_t ws_size,
                              hipStream_t stream) {
    const float* z = (const float*)d_in[0];
    const float* Wi = (const float*)d_in[1];
    const float* bi = (const float*)d_in[2];
    const float* Wh = (const float*)d_in[3];
    const float* bh = (const float*)d_in[4];
    const float* Wo = (const float*)d_in[5];
    const float* bo = (const float*)d_in[6];
    const int* perms = (const int*)d_in[7];
    float* out = (float*)d_out;
    float* wsf = (float*)d_ws;  // 15*1024 floats + 16 ints

    hipLaunchKernelGGL(build_tabs, dim3(1), dim3(256), 0, stream,
                       Wi, bi, Wh, bh, Wo, bo, perms, wsf);
    hipLaunchKernelGGL(flow_fwd, dim3(BN / 256), dim3(256), 0, stream,
                       z, wsf, out, out + (size_t)BN * 16);
}

// Round 6
// 122.280 us; speedup vs baseline: 2.1937x; 2.1937x over previous
//
#include <hip/hip_runtime.h>

#define BN 262144
#define LNUM 15
// slab: 151 stages x 72 floats; stage lin = l*10 + net*5 + st; stage 150 = copy of stage 0
#define NSTG 151

extern "C" __global__ void build_slab(
    const float* __restrict__ Wi, const float* __restrict__ bi,
    const float* __restrict__ Wh, const float* __restrict__ bh,
    const float* __restrict__ Wo, const float* __restrict__ bo,
    float* __restrict__ slab) {
    int idx = blockIdx.x * 256 + threadIdx.x;
    if (idx >= NSTG * 72) return;
    int sl = idx / 72, k = idx % 72;
    if (sl == NSTG - 1) sl = 0;                 // duplicate stage for tail prefetch
    const int l = sl / 10, r = sl % 10, net = r / 5, st = r % 5;
    const int nb = l * 2 + net;
    float v;
    if (k < 64) {
        if (st == 0)      v = Wi[nb * 64 + k];
        else if (st < 4)  v = Wh[(nb * 3 + (st - 1)) * 64 + k];
        else              v = Wo[nb * 64 + k];
    } else {
        const int o = k - 64;
        if (st == 0)      v = bi[nb * 8 + o];
        else if (st < 4)  v = bh[(nb * 3 + (st - 1)) * 8 + o];
        else              v = bo[nb * 8 + o];
    }
    slab[idx] = v;
}

// access float j of an 18-float4 VGPR buffer with compile-time j
#define WB(buf, k) ((k) % 4 == 0 ? buf[(k) / 4].x : (k) % 4 == 1 ? buf[(k) / 4].y \
                  : (k) % 4 == 2 ? buf[(k) / 4].z : buf[(k) / 4].w)

// issue 18 broadcast global_load_dwordx4 for the stage at float-offset foff
#define PREF(dst, foff)                                                      \
    {                                                                        \
        const float4* sp = reinterpret_cast<const float4*>(Wl + (foff));     \
        _Pragma("unroll") for (int j = 0; j < 18; ++j) dst[j] = sp[j];       \
    }

__device__ __forceinline__ void mv8(const float in[8], const float4 buf[18], float out[8]) {
#pragma unroll
    for (int o = 0; o < 8; ++o) out[o] = fmaf(in[0], WB(buf, o), WB(buf, 64 + o));
#pragma unroll
    for (int i = 1; i < 8; ++i)
#pragma unroll
        for (int o = 0; o < 8; ++o) out[o] = fmaf(in[i], WB(buf, i * 8 + o), out[o]);
}

__device__ __forceinline__ void lr8(float v[8]) {
#pragma unroll
    for (int o = 0; o < 8; ++o) v[o] = fmaxf(v[o], 0.01f * v[o]);
}

// 1 thread = 1 sample; weights VMEM-broadcast into ping-pong VGPR buffers,
// prefetched one stage ahead (kills the s_load serialization of r2/r5).
extern "C" __global__ void __launch_bounds__(256) flow_fwd(
    const float* __restrict__ z, const float* __restrict__ slab,
    const int* __restrict__ perms,
    float* __restrict__ outy, float* __restrict__ outld) {
    __shared__ float xs[256 * 17];   // private permute slot, stride 17 (odd)
    const int t = threadIdx.x;
    const long i = (long)blockIdx.x * 256 + t;
    float* __restrict__ myx = &xs[t * 17];

    float4 A[18], Bq[18];
    {
        const float* Wl = slab;
        PREF(A, 0)                    // stage (0,0,0)
    }
    float x[16];
    {
        const float4* zp = reinterpret_cast<const float4*>(z + i * 16);
        float4 a0 = zp[0], a1 = zp[1], a2 = zp[2], a3 = zp[3];
        x[0] = a0.x;  x[1] = a0.y;  x[2] = a0.z;  x[3] = a0.w;
        x[4] = a1.x;  x[5] = a1.y;  x[6] = a1.z;  x[7] = a1.w;
        x[8] = a2.x;  x[9] = a2.y;  x[10] = a2.z; x[11] = a2.w;
        x[12] = a3.x; x[13] = a3.y; x[14] = a3.z; x[15] = a3.w;
    }
    float ld = 0.f;

    for (int l = 0; l < LNUM; ++l) {
        const float* __restrict__ Wl = slab + l * 720;
        float h[8], g[8], sf[8], bf[8];
        // net 0 (log_s):  A, B, A, B, A   | net 1 (b): B, A, B, A, B
        PREF(Bq, 72)  mv8(x, A, h);  lr8(h);
        PREF(A, 144)  mv8(h, Bq, g); lr8(g);
        PREF(Bq, 216) mv8(g, A, h);  lr8(h);
        PREF(A, 288)  mv8(h, Bq, g); lr8(g);
        PREF(Bq, 360) mv8(g, A, sf);
        PREF(A, 432)  mv8(x, Bq, h); lr8(h);
        PREF(Bq, 504) mv8(h, A, g);  lr8(g);
        PREF(A, 576)  mv8(g, Bq, h); lr8(h);
        PREF(Bq, 648) mv8(h, A, g);  lr8(g);
        PREF(A, 720)  mv8(g, Bq, bf);        // also preloads next layer's stage 0

#pragma unroll
        for (int k = 0; k < 8; ++k) {
            const float cs = fminf(fmaxf(sf[k], -5.f), 5.f);
            ld += cs;
            x[8 + k] = fmaf(__expf(cs) + 1e-6f, x[8 + k], bf[k]);
        }
        // register permutation via private LDS slot (runtime uniform indices)
#pragma unroll
        for (int p = 0; p < 16; ++p) myx[p] = x[p];
        const int* pl = perms + l * 16;
#pragma unroll
        for (int j = 0; j < 16; ++j) x[j] = myx[pl[j]];
    }

    float* yrow = outy + i * 16;
    float4 o0, o1, o2, o3;
    o0.x = x[0];  o0.y = x[1];  o0.z = x[2];  o0.w = x[3];
    o1.x = x[4];  o1.y = x[5];  o1.z = x[6];  o1.w = x[7];
    o2.x = x[8];  o2.y = x[9];  o2.z = x[10]; o2.w = x[11];
    o3.x = x[12]; o3.y = x[13]; o3.z = x[14]; o3.w = x[15];
    reinterpret_cast<float4*>(yrow)[0] = o0;
    reinterpret_cast<float4*>(yrow)[1] = o1;
    reinterpret_cast<float4*>(yrow)[2] = o2;
    reinterpret_cast<float4*>(yrow)[3] = o3;
    outld[i] = ld;
}

extern "C" void kernel_launch(void* const* d_in, const int* in_sizes, int n_in,
                              void* d_out, int out_size, void* d_ws, size_t ws_size,
                              hipStream_t stream) {
    const float* z = (const float*)d_in[0];
    const float* Wi = (const float*)d_in[1];
    const float* bi = (const float*)d_in[2];
    const float* Wh = (const float*)d_in[3];
    const float* bh = (const float*)d_in[4];
    const float* Wo = (const float*)d_in[5];
    const float* bo = (const float*)d_in[6];
    const int* perms = (const int*)d_in[7];
    float* out = (float*)d_out;
    float* slab = (float*)d_ws;   // 151*72 floats = 43.5 KB

    hipLaunchKernelGGL(build_slab, dim3((NSTG * 72 + 255) / 256), dim3(256), 0, stream,
                       Wi, bi, Wh, bh, Wo, bo, slab);
    hipLaunchKernelGGL(flow_fwd, dim3(BN / 256), dim3(256), 0, stream,
                       z, slab, perms, out, out + (size_t)BN * 16);
}